// Round 16
// baseline (123.872 us; speedup 1.0000x reference)
//
#include <hip/hip_runtime.h>
#include <hip/hip_bf16.h>
#include <math.h>

// SupCon loss, N=8192 D=128 fp32 in, scalar fp32 out.
// Round 19: fold the reduce kernel into sim via last-block-done reduction.
// R18 (512 blocks x 8 tiles, XCD-bijective) won 97.4->93.8; reduce (~5us +
// gap) is now the biggest untouched item and it serializes behind the FULL
// sim grid, while row-tiles actually finish incrementally. Each of the 8
// blocks sharing row-tile ti: stores partials -> __syncthreads (drains
// stores) -> thread0 __threadfence + atomicAdd(cnt[ti]); the 8th block
// re-fences (acquire) and reduces ti's 128 rows (LDS hist + 16-slot
// butterfly + 1 atomicAdd to out). 63 of 64 reductions overlap other tiles'
// compute. prep zeroes out[0] + cnt[64]. Main sim path: R18-verbatim.

constexpr int N = 8192;
constexpr int D = 128;

typedef __attribute__((ext_vector_type(8))) short short8;  // 8 bf16 = 4 VGPRs
typedef __attribute__((ext_vector_type(4))) float f32x4;

constexpr float SELF_POISON = -50.0f;  // exp2(-50) ~ 9e-16; |s2| <= 14.43 real

__device__ __forceinline__ float fast_exp2(float x) {
#if __has_builtin(__builtin_amdgcn_exp2f)
    return __builtin_amdgcn_exp2f(x);
#else
    return __expf(x * 0.69314718056f);
#endif
}

// ---------------- prep: bf16 rows scaled into log2 domain, fragment layout --
// FbP uint index for element pair (row, k=2l): (row>>4)*1024 + (l>>2)*64 +
// (row&15)*4 + (l&3). Chunk chi = l>>2 holds k = 8*chi .. 8*chi+7 in order.
// Also zeroes out[0] and the 64 per-tile counters.
__global__ void prep_kernel(const float* __restrict__ F,
                            unsigned int* __restrict__ FbP,
                            float* __restrict__ out,
                            int* __restrict__ cnt) {
    if (blockIdx.x == 0) {
        if (threadIdx.x == 0) out[0] = 0.0f;
        if (threadIdx.x < 64) cnt[threadIdx.x] = 0;
    }
    int row = blockIdx.x * 4 + (threadIdx.x >> 6);
    int l = threadIdx.x & 63;
    float2 v = ((const float2*)(F + (size_t)row * D))[l];
    float ss = v.x * v.x + v.y * v.y;
#pragma unroll
    for (int off = 32; off > 0; off >>= 1) ss += __shfl_xor(ss, off);
    float sc = sqrtf(14.4269504089f / ss);  // 10 * log2(e), folded
    __hip_bfloat16 hx = __float2bfloat16(v.x * sc);
    __hip_bfloat16 hy = __float2bfloat16(v.y * sc);
    unsigned int ux = *(unsigned short*)&hx;
    unsigned int uy = *(unsigned short*)&hy;
    unsigned int idx = ((unsigned)(row >> 4) << 10) | ((unsigned)(l >> 2) << 6) |
                       ((unsigned)(row & 15) << 2) | (unsigned)(l & 3);
    FbP[idx] = ux | (uy << 16);
}

// ---------------- sim: full matrix, MFMA, fused last-block reduction --------
// 512 blocks: bid = g2 + 8*ti (XCD-bijective). Block (ti, g2): rows
// ti*128..+128 x B-tiles tj in [8*g2, 8*g2+8). A-frags in registers; B via
// the R15 double-buffer schedule. After partial stores, the last of ti's 8
// blocks reduces its 128 rows and accumulates into out[0].
#define LOADB(BUF, TJ, KK)                                          \
    _Pragma("unroll") for (int n_ = 0; n_ < 4; ++n_)                \
        BUF[n_] = P[((TJ) * 8 + wx * 4 + n_) * 256 + (KK) * 64 + l];

#define MFMASTEP(BUF, KK)                                           \
    _Pragma("unroll") for (int m_ = 0; m_ < 4; ++m_)                \
        _Pragma("unroll") for (int n_ = 0; n_ < 4; ++n_)            \
            acc[m_][n_] = __builtin_amdgcn_mfma_f32_16x16x32_bf16(  \
                Af[KK][m_], BUF[n_], acc[m_][n_], 0, 0, 0);

__global__ __launch_bounds__(256, 2) void sim_kernel(
    const short8* __restrict__ P, const int* __restrict__ labels,
    float* __restrict__ partE, float* __restrict__ partP,
    int* __restrict__ cnt, float* __restrict__ out) {
    __shared__ int hist[1024];
    __shared__ float ws4[4];
    __shared__ int isLast;

    const int g2 = blockIdx.x & 7;    // 8 column groups of 8 tiles
    const int ti = blockIdx.x >> 3;   // 64 row tiles
    const int tjs = g2 * 8;
    const int i0 = ti * 128;

    const int t = threadIdx.x, w = t >> 6, l = t & 63;
    const int c = l & 15, quad = l >> 4;    // MFMA lane split
    const int wy = w >> 1, wx = w & 1;      // 64x64 quadrant per wave

    // A fragments for the whole strip: 16 x 1KB coalesced loads, 64 VGPR.
    short8 Af[4][4];  // [kk][m]
#pragma unroll
    for (int kk = 0; kk < 4; ++kk)
#pragma unroll
        for (int m = 0; m < 4; ++m)
            Af[kk][m] = P[(ti * 8 + wy * 4 + m) * 256 + kk * 64 + l];

    // row labels for this wave's rows (strip-constant)
    int li[4][4];
#pragma unroll
    for (int m = 0; m < 4; ++m)
#pragma unroll
        for (int r = 0; r < 4; ++r)
            li[m][r] = labels[i0 + wy * 64 + m * 16 + quad * 4 + r];

    const bool selfQuad = (quad == (c >> 2));  // lane may hold self elements

    float RE[4][4] = {}, RP[4][4] = {};  // row partials, carried across strip

    short8 bfA[4], bfB[4];   // B-fragment double buffer (static indices only)
    LOADB(bfA, tjs, 0);      // prologue: kk0 and kk1 of first tile in flight
    LOADB(bfB, tjs, 1);

#pragma unroll 1
    for (int tj = tjs; tj < tjs + 8; ++tj) {
        const int j0 = tj * 128;
        int lj[4];
#pragma unroll
        for (int n = 0; n < 4; ++n) lj[n] = labels[j0 + wx * 64 + n * 16 + c];

        f32x4 acc[4][4] = {};
        const int tp = (tj < tjs + 7) ? tj + 1 : tjs;  // last prefetch harmless
        // steady state: bfA=kk0, bfB=kk1 already in flight (epilogue-covered)
        MFMASTEP(bfA, 0);
        LOADB(bfA, tj, 2);
        MFMASTEP(bfB, 1);
        LOADB(bfB, tj, 3);
        MFMASTEP(bfA, 2);
        LOADB(bfA, tp, 0);
        MFMASTEP(bfB, 3);
        LOADB(bfB, tp, 1);   // next tile's kk1 also rides under the epilogue

        // Diagonal tile: poison self elements so the clean epilogue naturally
        // zeroes them (exp2(-50)~0; the -50 entering RP is corrected at store).
        if (tj == ti && wy == wx) {
#pragma unroll
            for (int m = 0; m < 4; ++m)
#pragma unroll
                for (int r = 0; r < 4; ++r) {
                    bool cond = selfQuad && (r == (c & 3));
                    acc[m][m][r] = cond ? SELF_POISON : acc[m][m][r];
                }
        }

        // ---- minimal row-only epilogue: 5 insts per element ----
#pragma unroll
        for (int m = 0; m < 4; ++m) {
#pragma unroll
            for (int n = 0; n < 4; ++n) {
#pragma unroll
                for (int r = 0; r < 4; ++r) {
                    float s2 = acc[m][n][r];
                    RE[m][r] += fast_exp2(s2);
                    RP[m][r] += (li[m][r] == lj[n]) ? s2 : 0.0f;
                }
            }
        }
    }

    // strip end: row reduction across the 16 col-lanes, then PLAIN STORES to
    // this block+wave's private slice.
#pragma unroll
    for (int m = 0; m < 4; ++m)
#pragma unroll
        for (int r = 0; r < 4; ++r) {
#pragma unroll
            for (int off = 1; off < 16; off <<= 1) {
                RE[m][r] += __shfl_xor(RE[m][r], off);
                RP[m][r] += __shfl_xor(RP[m][r], off);
            }
        }
    if (c == 0) {
        // undo the diag poison injected into the positive-sums: exactly one
        // -50 per (m,r) row group in waves wy==wx of the diag-containing block
        // (block contains its diag tile iff ti>>3 == g2).
        if ((ti >> 3) == g2 && wy == wx) {
#pragma unroll
            for (int m = 0; m < 4; ++m)
#pragma unroll
                for (int r = 0; r < 4; ++r) RP[m][r] -= SELF_POISON;
        }
        const int slot = g2 * 2 + wx;  // 16 private slots per row
#pragma unroll
        for (int m = 0; m < 4; ++m)
#pragma unroll
            for (int r = 0; r < 4; ++r) {
                int gi = i0 + wy * 64 + m * 16 + quad * 4 + r;
                partE[(size_t)gi * 16 + slot] = RE[m][r];
                partP[(size_t)gi * 16 + slot] = RP[m][r];
            }
    }

    // ---- last-block-done reduction for this row-tile ----
    __syncthreads();  // drains all waves' partial stores (vmcnt(0) + barrier)
    if (t == 0) {
        __threadfence();                       // publish stores device-wide
        isLast = (atomicAdd(&cnt[ti], 1) == 7);
    }
    __syncthreads();
    if (!isLast) return;
    __threadfence();  // acquire: see the other 7 blocks' partial stores

    // label histogram in LDS (1000 classes < 1024)
#pragma unroll
    for (int k = 0; k < 4; ++k) hist[t + 256 * k] = 0;
    __syncthreads();
#pragma unroll
    for (int k = 0; k < 32; ++k) atomicAdd(&hist[labels[t + 256 * k]], 1);
    __syncthreads();

    // 8 half-waves x 16 iterations = 128 rows; 16 slots per row in lanes 0-15.
    const int hw = t >> 5, sl = l & 31;
    float a = 0.0f;
#pragma unroll 1
    for (int it = 0; it < 16; ++it) {
        int row = i0 + it * 8 + hw;
        float se = 0.0f, sp = 0.0f;
        if (sl < 16) {
            se = partE[(size_t)row * 16 + sl];
            sp = partP[(size_t)row * 16 + sl];
        }
#pragma unroll
        for (int off = 1; off < 32; off <<= 1) {
            se += __shfl_xor(se, off);
            sp += __shfl_xor(sp, off);
        }
        if (sl == 0) {
            int cn = hist[labels[row]] - 1;
            if (cn > 0)
                a += logf(se + 1e-9f) - 0.69314718056f * sp / (float)cn;
        }
    }
    // block reduce (only lanes sl==0 carry nonzero a)
#pragma unroll
    for (int off = 1; off < 64; off <<= 1) a += __shfl_xor(a, off);
    if (l == 0) ws4[w] = a;
    __syncthreads();
    if (t == 0) {
        float s = ws4[0] + ws4[1] + ws4[2] + ws4[3];
        atomicAdd(out, s * (1.0f / (float)N));
    }
}

extern "C" void kernel_launch(void* const* d_in, const int* in_sizes, int n_in,
                              void* d_out, int out_size, void* d_ws, size_t ws_size,
                              hipStream_t stream) {
    const float* F      = (const float*)d_in[0];
    const int*   labels = (const int*)d_in[1];
    float* out = (float*)d_out;

    unsigned int* FbP = (unsigned int*)d_ws;                         // 2 MB
    float* partE = (float*)((char*)d_ws + (size_t)2 * 1024 * 1024);  // 512 KB
    float* partP = partE + (size_t)N * 16;                           // 512 KB
    int*   cnt   = (int*)(partP + (size_t)N * 16);                   // 256 B

    prep_kernel<<<N / 4, 256, 0, stream>>>(F, FbP, out, cnt);
    sim_kernel<<<512, 256, 0, stream>>>((const short8*)FbP, labels, partE,
                                        partP, cnt, out);
}

// Round 17
// 93.601 us; speedup vs baseline: 1.3234x; 1.3234x over previous
//
#include <hip/hip_runtime.h>
#include <hip/hip_bf16.h>
#include <math.h>

// SupCon loss, N=8192 D=128 fp32 in, scalar fp32 out.
// Round 20: REVERT R19's fused last-block reduction -- its __threadfence
// pairs (device-scope, cross-XCD) compile to L2 writeback/invalidate and
// repeatedly flushed the L2 residency sim's data path depends on (sim 33 ->
// 78-100us, MfmaUtil 7.5%). Lesson: on non-coherent per-XCD L2s, single-
// kernel producer/consumer fusion costs more in coherence traffic than the
// ~5us launch it saves. Back to R18 (93.8us session best) verbatim, plus one
// zero-cost addition: prep->sim PRODUCER L2 LOCALITY. In R18's XCD-bijective
// sim mapping, B-tiles [8*g2, 8*g2+8) are read ONLY by XCD g2; remap prep's
// block->row assignment (xcd = bid&7 writes rows [1024*xcd, 1024*(xcd+1)))
// so the same XCD that produces those rows consumes them as B-tiles -- warm
// L2 on sim's first touch. Pure index permutation, no new instructions.

constexpr int N = 8192;
constexpr int D = 128;

typedef __attribute__((ext_vector_type(8))) short short8;  // 8 bf16 = 4 VGPRs
typedef __attribute__((ext_vector_type(4))) float f32x4;

constexpr float SELF_POISON = -50.0f;  // exp2(-50) ~ 9e-16; |s2| <= 14.43 real

__device__ __forceinline__ float fast_exp2(float x) {
#if __has_builtin(__builtin_amdgcn_exp2f)
    return __builtin_amdgcn_exp2f(x);
#else
    return __expf(x * 0.69314718056f);
#endif
}

// ---------------- prep: bf16 rows scaled into log2 domain, fragment layout --
// FbP uint index for element pair (row, k=2l): (row>>4)*1024 + (l>>2)*64 +
// (row&15)*4 + (l&3). Chunk chi = l>>2 holds k = 8*chi .. 8*chi+7 in order.
// Block->row map is XCD-aligned with sim's consumer mapping: block b writes
// rows (b&7)*1024 + (b>>3)*4 .. +3, so XCD x produces exactly the rows that
// sim's col-group g2==x blocks (also on XCD x) consume as B-tiles.
// Also zeroes out[0] (stream-ordered before reduce's atomicAdd).
__global__ void prep_kernel(const float* __restrict__ F,
                            unsigned int* __restrict__ FbP,
                            float* __restrict__ out) {
    if (blockIdx.x == 0 && threadIdx.x == 0) out[0] = 0.0f;
    int row = (blockIdx.x & 7) * 1024 + (blockIdx.x >> 3) * 4 +
              (threadIdx.x >> 6);
    int l = threadIdx.x & 63;
    float2 v = ((const float2*)(F + (size_t)row * D))[l];
    float ss = v.x * v.x + v.y * v.y;
#pragma unroll
    for (int off = 32; off > 0; off >>= 1) ss += __shfl_xor(ss, off);
    float sc = sqrtf(14.4269504089f / ss);  // 10 * log2(e), folded
    __hip_bfloat16 hx = __float2bfloat16(v.x * sc);
    __hip_bfloat16 hy = __float2bfloat16(v.y * sc);
    unsigned int ux = *(unsigned short*)&hx;
    unsigned int uy = *(unsigned short*)&hy;
    unsigned int idx = ((unsigned)(row >> 4) << 10) | ((unsigned)(l >> 2) << 6) |
                       ((unsigned)(row & 15) << 2) | (unsigned)(l & 3);
    FbP[idx] = ux | (uy << 16);
}

// ---------------- sim: full matrix, MFMA, no LDS/barriers/atomics -----------
// 512 blocks: bid = g2 + 8*ti (XCD-bijective: all 64 blocks of col-group g2
// land on XCD g2 under bid%8 round-robin). Block (ti, g2): rows ti*128..+128
// x B-tiles tj in [8*g2, 8*g2+8). A-frags in registers, loaded ONCE for 8
// tiles; B streamed via the R15 double-buffer schedule.
#define LOADB(BUF, TJ, KK)                                          \
    _Pragma("unroll") for (int n_ = 0; n_ < 4; ++n_)                \
        BUF[n_] = P[((TJ) * 8 + wx * 4 + n_) * 256 + (KK) * 64 + l];

#define MFMASTEP(BUF, KK)                                           \
    _Pragma("unroll") for (int m_ = 0; m_ < 4; ++m_)                \
        _Pragma("unroll") for (int n_ = 0; n_ < 4; ++n_)            \
            acc[m_][n_] = __builtin_amdgcn_mfma_f32_16x16x32_bf16(  \
                Af[KK][m_], BUF[n_], acc[m_][n_], 0, 0, 0);

__global__ __launch_bounds__(256, 2) void sim_kernel(
    const short8* __restrict__ P, const int* __restrict__ labels,
    float* __restrict__ partE, float* __restrict__ partP) {
    const int g2 = blockIdx.x & 7;    // 8 column groups of 8 tiles
    const int ti = blockIdx.x >> 3;   // 64 row tiles
    const int tjs = g2 * 8;
    const int i0 = ti * 128;

    const int t = threadIdx.x, w = t >> 6, l = t & 63;
    const int c = l & 15, quad = l >> 4;    // MFMA lane split
    const int wy = w >> 1, wx = w & 1;      // 64x64 quadrant per wave

    // A fragments for the whole strip: 16 x 1KB coalesced loads, 64 VGPR.
    short8 Af[4][4];  // [kk][m]
#pragma unroll
    for (int kk = 0; kk < 4; ++kk)
#pragma unroll
        for (int m = 0; m < 4; ++m)
            Af[kk][m] = P[(ti * 8 + wy * 4 + m) * 256 + kk * 64 + l];

    // row labels for this wave's rows (strip-constant)
    int li[4][4];
#pragma unroll
    for (int m = 0; m < 4; ++m)
#pragma unroll
        for (int r = 0; r < 4; ++r)
            li[m][r] = labels[i0 + wy * 64 + m * 16 + quad * 4 + r];

    const bool selfQuad = (quad == (c >> 2));  // lane may hold self elements

    float RE[4][4] = {}, RP[4][4] = {};  // row partials, carried across strip

    short8 bfA[4], bfB[4];   // B-fragment double buffer (static indices only)
    LOADB(bfA, tjs, 0);      // prologue: kk0 and kk1 of first tile in flight
    LOADB(bfB, tjs, 1);

#pragma unroll 1
    for (int tj = tjs; tj < tjs + 8; ++tj) {
        const int j0 = tj * 128;
        int lj[4];
#pragma unroll
        for (int n = 0; n < 4; ++n) lj[n] = labels[j0 + wx * 64 + n * 16 + c];

        f32x4 acc[4][4] = {};
        const int tp = (tj < tjs + 7) ? tj + 1 : tjs;  // last prefetch harmless
        // steady state: bfA=kk0, bfB=kk1 already in flight (epilogue-covered)
        MFMASTEP(bfA, 0);
        LOADB(bfA, tj, 2);
        MFMASTEP(bfB, 1);
        LOADB(bfB, tj, 3);
        MFMASTEP(bfA, 2);
        LOADB(bfA, tp, 0);
        MFMASTEP(bfB, 3);
        LOADB(bfB, tp, 1);   // next tile's kk1 also rides under the epilogue

        // Diagonal tile: poison self elements so the clean epilogue naturally
        // zeroes them (exp2(-50)~0; the -50 entering RP is corrected at store).
        if (tj == ti && wy == wx) {
#pragma unroll
            for (int m = 0; m < 4; ++m)
#pragma unroll
                for (int r = 0; r < 4; ++r) {
                    bool cond = selfQuad && (r == (c & 3));
                    acc[m][m][r] = cond ? SELF_POISON : acc[m][m][r];
                }
        }

        // ---- minimal row-only epilogue: 5 insts per element ----
        // (covers the latency of the two next-tile prefetches above)
#pragma unroll
        for (int m = 0; m < 4; ++m) {
#pragma unroll
            for (int n = 0; n < 4; ++n) {
#pragma unroll
                for (int r = 0; r < 4; ++r) {
                    float s2 = acc[m][n][r];
                    RE[m][r] += fast_exp2(s2);
                    RP[m][r] += (li[m][r] == lj[n]) ? s2 : 0.0f;
                }
            }
        }
    }

    // strip end: row reduction across the 16 col-lanes, then PLAIN STORES to
    // this block+wave's private slice. No atomics anywhere in this kernel.
#pragma unroll
    for (int m = 0; m < 4; ++m)
#pragma unroll
        for (int r = 0; r < 4; ++r) {
#pragma unroll
            for (int off = 1; off < 16; off <<= 1) {
                RE[m][r] += __shfl_xor(RE[m][r], off);
                RP[m][r] += __shfl_xor(RP[m][r], off);
            }
        }
    if (c == 0) {
        // undo the diag poison injected into the positive-sums: exactly one
        // -50 per (m,r) row group in waves wy==wx of the diag-containing block
        // (block contains its diag tile iff ti>>3 == g2).
        if ((ti >> 3) == g2 && wy == wx) {
#pragma unroll
            for (int m = 0; m < 4; ++m)
#pragma unroll
                for (int r = 0; r < 4; ++r) RP[m][r] -= SELF_POISON;
        }
        const int slot = g2 * 2 + wx;  // 16 private slots per row
#pragma unroll
        for (int m = 0; m < 4; ++m)
#pragma unroll
            for (int r = 0; r < 4; ++r) {
                int gi = i0 + wy * 64 + m * 16 + quad * 4 + r;
                partE[(size_t)gi * 16 + slot] = RE[m][r];
                partP[(size_t)gi * 16 + slot] = RP[m][r];
            }
    }
}

// ---------------- reduce: 128 blocks; one row per 32-lane half-wave ---------
// Builds the label histogram in LDS, sums the 16 partials per row, one scaled
// atomicAdd per block into out[0].
__global__ void reduce_kernel(const float* __restrict__ partE,
                              const float* __restrict__ partP,
                              const int* __restrict__ labels,
                              float* __restrict__ out) {
    __shared__ int hist[1024];
    __shared__ float ws4[4];
    const int t = threadIdx.x, w = t >> 6, l = t & 63;
    const int half = l >> 5, sl = l & 31;
    const int rbase = blockIdx.x * 64 + w * 16;  // 64 rows/block, 16/wave

#pragma unroll
    for (int k = 0; k < 4; ++k) hist[t + 256 * k] = 0;
    __syncthreads();
#pragma unroll
    for (int k = 0; k < 32; ++k) atomicAdd(&hist[labels[t + 256 * k]], 1);
    __syncthreads();

    float a = 0.0f;
#pragma unroll
    for (int it = 0; it < 8; ++it) {
        int row = rbase + it * 2 + half;
        float se = 0.0f, sp = 0.0f;
        if (sl < 16) {
            se = partE[(size_t)row * 16 + sl];
            sp = partP[(size_t)row * 16 + sl];
        }
#pragma unroll
        for (int off = 1; off < 32; off <<= 1) {
            se += __shfl_xor(se, off);
            sp += __shfl_xor(sp, off);
        }
        if (sl == 0) {
            int cnt = hist[labels[row]] - 1;
            if (cnt > 0)
                a += logf(se + 1e-9f) - 0.69314718056f * sp / (float)cnt;
        }
    }
    // wave reduce (only lanes sl==0 carry nonzero a)
#pragma unroll
    for (int off = 1; off < 64; off <<= 1) a += __shfl_xor(a, off);
    if (l == 0) ws4[w] = a;
    __syncthreads();
    if (t == 0) {
        float s = ws4[0] + ws4[1] + ws4[2] + ws4[3];
        atomicAdd(out, s * (1.0f / (float)N));
    }
}

extern "C" void kernel_launch(void* const* d_in, const int* in_sizes, int n_in,
                              void* d_out, int out_size, void* d_ws, size_t ws_size,
                              hipStream_t stream) {
    const float* F      = (const float*)d_in[0];
    const int*   labels = (const int*)d_in[1];
    float* out = (float*)d_out;

    unsigned int* FbP = (unsigned int*)d_ws;                         // 2 MB
    float* partE = (float*)((char*)d_ws + (size_t)2 * 1024 * 1024);  // 512 KB
    float* partP = partE + (size_t)N * 16;                           // 512 KB

    prep_kernel<<<N / 4, 256, 0, stream>>>(F, FbP, out);
    sim_kernel<<<512, 256, 0, stream>>>((const short8*)FbP, labels, partE,
                                        partP);
    reduce_kernel<<<128, 256, 0, stream>>>(partE, partP, labels, out);
}